// Round 6
// baseline (306.939 us; speedup 1.0000x reference)
//
#include <hip/hip_runtime.h>
#include <math.h>

// Problem constants (match reference setup_inputs)
constexpr int S = 4096;   // sequence length
constexpr int D = 1024;   // d_model
constexpr int B = 4;      // batch
constexpr int F = 64;     // num frequencies

constexpr float TWO_PI = 6.28318530717958647692f;

typedef __attribute__((ext_vector_type(4))) float fv4;

// ---------------------------------------------------------------------------
// Kernel 1: P[d] = sum_m A[m,d] * cos(w_m t);  Q[d] = sum_m A[m,d] * sin(w_m t)
// ws[0..D) = P ; ws[D..2D) = Q
// ---------------------------------------------------------------------------
__global__ __launch_bounds__(256)
void we_coef_kernel(const float* __restrict__ amp,
                    const float* __restrict__ freq,
                    const void*  __restrict__ t_ptr,
                    float* __restrict__ ws)
{
    __shared__ float cm[F], sm[F];

    const int tid = threadIdx.x;
    const int d   = blockIdx.x * 256 + tid;

    // decode t robustly (int32 / int64-low-word / float32-bits)
    int ti = *(const int*)t_ptr;
    float t = (ti > -1048576 && ti < 1048576) ? (float)ti : __int_as_float(ti);

    if (tid < F) {
        float sv, cv;
        sincosf(TWO_PI * freq[tid] * t, &sv, &cv);
        cm[tid] = cv;
        sm[tid] = sv;
    }
    __syncthreads();

    float P = 0.f, Q = 0.f;
    #pragma unroll
    for (int m = 0; m < F; ++m) {
        const float a = amp[m * D + d];
        P = fmaf(a, cm[m], P);
        Q = fmaf(a, sm[m], Q);
    }
    ws[d]     = P;
    ws[D + d] = Q;
}

// ---------------------------------------------------------------------------
// Kernel 2: one block per s-row; 256 threads = D/4 float4 columns.
//   real[b,s,d] = (cos k_s * P[d] + sin k_s * Q[d]) * emb[tok[b,s], d]
//   imag[b,s,d] = (sin k_s * P[d] - cos k_s * Q[d]) * emb[tok[b,s], d]
// Nontemporal stores keep the 134 MB output stream out of L2 so the
// embedding table stays cache-resident for the gathers.
// ---------------------------------------------------------------------------
constexpr int D4 = D / 4; // 256 float4 columns

__global__ __launch_bounds__(256, 8)
void we_main_kernel(const int* __restrict__ tokens,
                    const float* __restrict__ emb,
                    const float* __restrict__ ws,
                    float* __restrict__ out)
{
    const int tid = threadIdx.x;
    const int s   = blockIdx.x;

    const fv4* __restrict__ emb4 = (const fv4*)emb;
    const fv4* __restrict__ P4p  = (const fv4*)ws;
    const fv4* __restrict__ Q4p  = (const fv4*)(ws + D);
    fv4* __restrict__ out4       = (fv4*)out;

    // token ids (wave-uniform scalar loads); issue gathers before any VALU
    const int r0 = tokens[0 * S + s];
    const int r1 = tokens[1 * S + s];
    const int r2 = tokens[2 * S + s];
    const int r3 = tokens[3 * S + s];
    const fv4 e0 = emb4[(size_t)r0 * D4 + tid];
    const fv4 e1 = emb4[(size_t)r1 * D4 + tid];
    const fv4 e2 = emb4[(size_t)r2 * D4 + tid];
    const fv4 e3 = emb4[(size_t)r3 * D4 + tid];

    const fv4 P = P4p[tid];
    const fv4 Q = Q4p[tid];

    float sn, cs;
    sincosf(TWO_PI * (float)s * (1.0f / (float)S), &sn, &cs);

    fv4 rc, ic;
    rc = cs * P + sn * Q;
    ic = sn * P - cs * Q;

    const size_t plane4 = (size_t)B * S * D4;   // imag-plane offset in fv4s
    const size_t o0 = ((size_t)(0 * S + s)) * D4 + tid;
    const size_t o1 = ((size_t)(1 * S + s)) * D4 + tid;
    const size_t o2 = ((size_t)(2 * S + s)) * D4 + tid;
    const size_t o3 = ((size_t)(3 * S + s)) * D4 + tid;

    __builtin_nontemporal_store(rc * e0, &out4[o0]);
    __builtin_nontemporal_store(rc * e1, &out4[o1]);
    __builtin_nontemporal_store(rc * e2, &out4[o2]);
    __builtin_nontemporal_store(rc * e3, &out4[o3]);
    __builtin_nontemporal_store(ic * e0, &out4[plane4 + o0]);
    __builtin_nontemporal_store(ic * e1, &out4[plane4 + o1]);
    __builtin_nontemporal_store(ic * e2, &out4[plane4 + o2]);
    __builtin_nontemporal_store(ic * e3, &out4[plane4 + o3]);
}

extern "C" void kernel_launch(void* const* d_in, const int* in_sizes, int n_in,
                              void* d_out, int out_size, void* d_ws, size_t ws_size,
                              hipStream_t stream) {
    const int*   tokens = (const int*)  d_in[0];
    const void*  t_ptr  =               d_in[1];
    const float* emb    = (const float*)d_in[2];
    const float* amp    = (const float*)d_in[3];
    const float* freq   = (const float*)d_in[4];
    float*       out    = (float*)d_out;
    float*       ws     = (float*)d_ws;

    we_coef_kernel<<<dim3(D / 256), dim3(256), 0, stream>>>(amp, freq, t_ptr, ws);
    we_main_kernel<<<dim3(S), dim3(256), 0, stream>>>(tokens, emb, ws, out);
}